// Round 1
// baseline (339.313 us; speedup 1.0000x reference)
//
#include <hip/hip_runtime.h>

#define VOCAB 1000000
#define NUM_TABLES 10
#define OUT_SIZE 26
#define RBLOCKS_PER_TABLE 64
#define RTHREADS 256

__global__ void zero_kernel(unsigned int* __restrict__ hist, float* __restrict__ out) {
    int i = blockIdx.x * blockDim.x + threadIdx.x;
    int n4 = VOCAB / 4;
    if (i < n4) ((uint4*)hist)[i] = make_uint4(0u, 0u, 0u, 0u);
    if (i < OUT_SIZE) out[i] = 0.0f;
}

__global__ void hist_kernel(const int* __restrict__ idx, unsigned int* __restrict__ hist, int n) {
    int i = blockIdx.x * blockDim.x + threadIdx.x;
    int i4 = i * 4;
    if (i4 + 3 < n) {
        int4 v = ((const int4*)idx)[i];
        atomicAdd(&hist[v.x], 1u);
        atomicAdd(&hist[v.y], 1u);
        atomicAdd(&hist[v.z], 1u);
        atomicAdd(&hist[v.w], 1u);
    } else {
        for (int j = i4; j < n; ++j) atomicAdd(&hist[idx[j]], 1u);
    }
}

__device__ inline float wave_reduce(float v) {
#pragma unroll
    for (int o = 32; o > 0; o >>= 1) v += __shfl_down(v, o, 64);
    return v;
}

__global__ void __launch_bounds__(RTHREADS) reduce_kernel(const float* __restrict__ W,
                                                          const unsigned int* __restrict__ hist,
                                                          float* __restrict__ out) {
    const int t = blockIdx.x / RBLOCKS_PER_TABLE;
    const int b = blockIdx.x % RBLOCKS_PER_TABLE;
    const float4* __restrict__ W4 = (const float4*)(W + (size_t)t * VOCAB * 3);
    const uint4* __restrict__ h4 = (const uint4*)hist;
    const int ngroups = VOCAB / 4;  // 250000 groups of 4 rows
    float a0 = 0.f, a1 = 0.f, a2 = 0.f;
    const int stride = RBLOCKS_PER_TABLE * RTHREADS;
    for (int g = b * RTHREADS + (int)threadIdx.x; g < ngroups; g += stride) {
        uint4 c4 = h4[g];
        float4 w0 = W4[3 * g + 0];  // r0.xyz, r1.x
        float4 w1 = W4[3 * g + 1];  // r1.yz,  r2.xy
        float4 w2 = W4[3 * g + 2];  // r2.z,   r3.xyz
        float c0 = (float)c4.x, c1 = (float)c4.y, c2 = (float)c4.z, c3 = (float)c4.w;
        a0 += c0 * w0.x + c1 * w0.w + c2 * w1.z + c3 * w2.y;
        a1 += c0 * w0.y + c1 * w1.x + c2 * w1.w + c3 * w2.z;
        a2 += c0 * w0.z + c1 * w1.y + c2 * w2.x + c3 * w2.w;
    }
    a0 = wave_reduce(a0);
    a1 = wave_reduce(a1);
    a2 = wave_reduce(a2);
    __shared__ float s[3][4];
    int wave = threadIdx.x >> 6;
    int lane = threadIdx.x & 63;
    if (lane == 0) { s[0][wave] = a0; s[1][wave] = a1; s[2][wave] = a2; }
    __syncthreads();
    if (threadIdx.x == 0) {
        float r0 = s[0][0] + s[0][1] + s[0][2] + s[0][3];
        float r1 = s[1][0] + s[1][1] + s[1][2] + s[1][3];
        float r2 = s[2][0] + s[2][1] + s[2][2] + s[2][3];
        if (t == 5) {
            atomicAdd(&out[15], r0 + r1 + r2);
        } else if (t == 6) {
            atomicAdd(&out[16], r0 + r1 + r2);
        } else {
            int base = (t < 5) ? t * 3 : 17 + (t - 7) * 3;
            atomicAdd(&out[base + 0], r0);
            atomicAdd(&out[base + 1], r1);
            atomicAdd(&out[base + 2], r2);
        }
    }
}

extern "C" void kernel_launch(void* const* d_in, const int* in_sizes, int n_in,
                              void* d_out, int out_size, void* d_ws, size_t ws_size,
                              hipStream_t stream) {
    const int* eb_input = (const int*)d_in[0];
    // d_in[1] (eb_offset) is irrelevant: summing over all bags == summing over all indices.
    const float* W = (const float*)d_in[2];
    float* out = (float*)d_out;
    unsigned int* hist = (unsigned int*)d_ws;  // 1M u32 = 4 MB
    int n_idx = in_sizes[0];

    int zblocks = (VOCAB / 4 + 255) / 256;
    zero_kernel<<<zblocks, 256, 0, stream>>>(hist, out);

    int hthreads = (n_idx + 3) / 4;
    int hblocks = (hthreads + 255) / 256;
    hist_kernel<<<hblocks, 256, 0, stream>>>(eb_input, hist, n_idx);

    reduce_kernel<<<NUM_TABLES * RBLOCKS_PER_TABLE, RTHREADS, 0, stream>>>(W, hist, out);
}

// Round 2
// 251.135 us; speedup vs baseline: 1.3511x; 1.3511x over previous
//
#include <hip/hip_runtime.h>

#define VOCAB 1000000
#define NUM_TABLES 10
#define OUT_SIZE 26
#define BUCKET_BITS 12
#define BINS_PER_BUCKET 4096
#define NBUCKETS 245            // ceil(1e6 / 4096)
#define CAPACITY 18432          // per-bucket scatter capacity (u16); mean 16327 + ~16 sigma
#define FILL_STRIDE 16          // u32 per fill counter -> 64B apart (no false sharing on atomics)
#define RBLOCKS_PER_TABLE 128
#define RTHREADS 256

// ---------------- fast path ----------------

__global__ void zero_small_kernel(unsigned int* __restrict__ fill, float* __restrict__ out) {
    int i = blockIdx.x * blockDim.x + threadIdx.x;
    if (i < NBUCKETS * FILL_STRIDE) fill[i] = 0u;
    if (i < OUT_SIZE) out[i] = 0.0f;
}

__global__ void __launch_bounds__(256) scatter_kernel(const int* __restrict__ idx, int n,
                                                      unsigned int* __restrict__ fill,
                                                      unsigned short* __restrict__ scat) {
    __shared__ unsigned int lcount[NBUCKETS];
    __shared__ unsigned int lbase[NBUCKETS];
    for (int i = threadIdx.x; i < NBUCKETS; i += 256) lcount[i] = 0u;
    __syncthreads();

    const int4* idx4 = (const int4*)idx;
    const int n4 = n >> 2;
    const int b4 = blockIdx.x * 1024;   // block covers 1024 int4 = 4096 indices
    int4 q[4];
    bool val[4];
#pragma unroll
    for (int j = 0; j < 4; ++j) {
        int i4 = b4 + j * 256 + (int)threadIdx.x;
        val[j] = (i4 < n4);
        if (val[j]) q[j] = idx4[i4];
    }
    // pass 1: count buckets in LDS
#pragma unroll
    for (int j = 0; j < 4; ++j) {
        if (val[j]) {
            atomicAdd(&lcount[(unsigned)q[j].x >> BUCKET_BITS], 1u);
            atomicAdd(&lcount[(unsigned)q[j].y >> BUCKET_BITS], 1u);
            atomicAdd(&lcount[(unsigned)q[j].z >> BUCKET_BITS], 1u);
            atomicAdd(&lcount[(unsigned)q[j].w >> BUCKET_BITS], 1u);
        }
    }
    if (blockIdx.x == 0 && threadIdx.x == 0) {
        for (int i = n4 << 2; i < n; ++i)
            atomicAdd(&lcount[(unsigned)idx[i] >> BUCKET_BITS], 1u);
    }
    __syncthreads();
    // reserve global ranges (one atomic per nonzero bucket per block)
    for (int i = threadIdx.x; i < NBUCKETS; i += 256) {
        unsigned c = lcount[i];
        lbase[i] = c ? atomicAdd(&fill[i * FILL_STRIDE], c) : 0u;
    }
    __syncthreads();
    for (int i = threadIdx.x; i < NBUCKETS; i += 256) lcount[i] = 0u;
    __syncthreads();
    // pass 2: scatter low 12 bits as u16
#pragma unroll
    for (int j = 0; j < 4; ++j) {
        if (val[j]) {
            int vv[4] = {q[j].x, q[j].y, q[j].z, q[j].w};
#pragma unroll
            for (int e = 0; e < 4; ++e) {
                unsigned u = (unsigned)vv[e];
                unsigned bkt = u >> BUCKET_BITS;
                unsigned pos = lbase[bkt] + atomicAdd(&lcount[bkt], 1u);
                if (pos < CAPACITY)
                    scat[(size_t)bkt * CAPACITY + pos] = (unsigned short)(u & (BINS_PER_BUCKET - 1));
            }
        }
    }
    if (blockIdx.x == 0 && threadIdx.x == 0) {
        for (int i = n4 << 2; i < n; ++i) {
            unsigned u = (unsigned)idx[i];
            unsigned bkt = u >> BUCKET_BITS;
            unsigned pos = lbase[bkt] + atomicAdd(&lcount[bkt], 1u);
            if (pos < CAPACITY)
                scat[(size_t)bkt * CAPACITY + pos] = (unsigned short)(u & (BINS_PER_BUCKET - 1));
        }
    }
}

__global__ void __launch_bounds__(256) bucket_hist_kernel(const unsigned short* __restrict__ scat,
                                                          const unsigned int* __restrict__ fill,
                                                          unsigned int* __restrict__ hist) {
    __shared__ unsigned int h[BINS_PER_BUCKET];
    const int b = blockIdx.x;
    for (int i = threadIdx.x; i < BINS_PER_BUCKET; i += 256) h[i] = 0u;
    __syncthreads();
    unsigned count = fill[b * FILL_STRIDE];
    if (count > CAPACITY) count = CAPACITY;
    const unsigned int* p32 = (const unsigned int*)(scat + (size_t)b * CAPACITY);
    unsigned npairs = count >> 1;
    for (unsigned i = threadIdx.x; i < npairs; i += 256) {
        unsigned u = p32[i];
        atomicAdd(&h[u & 0xffffu], 1u);
        atomicAdd(&h[u >> 16], 1u);
    }
    if ((count & 1u) && threadIdx.x == 0) {
        unsigned short last = scat[(size_t)b * CAPACITY + count - 1];
        atomicAdd(&h[last], 1u);
    }
    __syncthreads();
    int nb = min(BINS_PER_BUCKET, VOCAB - b * BINS_PER_BUCKET);
    for (int i = threadIdx.x; i < nb; i += 256)
        hist[b * BINS_PER_BUCKET + i] = h[i];
}

__device__ inline float wave_reduce(float v) {
#pragma unroll
    for (int o = 32; o > 0; o >>= 1) v += __shfl_down(v, o, 64);
    return v;
}

__device__ inline void out_store(float* out, int t, float r0, float r1, float r2) {
    if (t == 5) {
        atomicAdd(&out[15], r0 + r1 + r2);
    } else if (t == 6) {
        atomicAdd(&out[16], r0 + r1 + r2);
    } else {
        int base = (t < 5) ? t * 3 : 17 + (t - 7) * 3;
        atomicAdd(&out[base + 0], r0);
        atomicAdd(&out[base + 1], r1);
        atomicAdd(&out[base + 2], r2);
    }
}

__global__ void __launch_bounds__(RTHREADS) reduce_kernel(const float* __restrict__ W,
                                                          const unsigned int* __restrict__ hist,
                                                          float* __restrict__ out) {
    const int t = blockIdx.x / RBLOCKS_PER_TABLE;
    const int b = blockIdx.x % RBLOCKS_PER_TABLE;
    const float4* __restrict__ W4 = (const float4*)(W + (size_t)t * VOCAB * 3);
    const uint4* __restrict__ h4 = (const uint4*)hist;
    const int ngroups = VOCAB / 4;  // 250000 groups of 4 rows
    float a0 = 0.f, a1 = 0.f, a2 = 0.f;
    const int stride = RBLOCKS_PER_TABLE * RTHREADS;
    for (int g = b * RTHREADS + (int)threadIdx.x; g < ngroups; g += stride) {
        uint4 c4 = h4[g];
        float4 w0 = W4[3 * g + 0];
        float4 w1 = W4[3 * g + 1];
        float4 w2 = W4[3 * g + 2];
        float c0 = (float)c4.x, c1 = (float)c4.y, c2 = (float)c4.z, c3 = (float)c4.w;
        a0 += c0 * w0.x + c1 * w0.w + c2 * w1.z + c3 * w2.y;
        a1 += c0 * w0.y + c1 * w1.x + c2 * w1.w + c3 * w2.z;
        a2 += c0 * w0.z + c1 * w1.y + c2 * w2.x + c3 * w2.w;
    }
    a0 = wave_reduce(a0);
    a1 = wave_reduce(a1);
    a2 = wave_reduce(a2);
    __shared__ float s[3][4];
    int wave = threadIdx.x >> 6;
    int lane = threadIdx.x & 63;
    if (lane == 0) { s[0][wave] = a0; s[1][wave] = a1; s[2][wave] = a2; }
    __syncthreads();
    if (threadIdx.x == 0) {
        out_store(out, t,
                  s[0][0] + s[0][1] + s[0][2] + s[0][3],
                  s[1][0] + s[1][1] + s[1][2] + s[1][3],
                  s[2][0] + s[2][1] + s[2][2] + s[2][3]);
    }
}

// ---------------- fallback path (R1, proven) ----------------

__global__ void zero_kernel_fb(unsigned int* __restrict__ hist, float* __restrict__ out) {
    int i = blockIdx.x * blockDim.x + threadIdx.x;
    int n4 = VOCAB / 4;
    if (i < n4) ((uint4*)hist)[i] = make_uint4(0u, 0u, 0u, 0u);
    if (i < OUT_SIZE) out[i] = 0.0f;
}

__global__ void hist_kernel_fb(const int* __restrict__ idx, unsigned int* __restrict__ hist, int n) {
    int i = blockIdx.x * blockDim.x + threadIdx.x;
    int i4 = i * 4;
    if (i4 + 3 < n) {
        int4 v = ((const int4*)idx)[i];
        atomicAdd(&hist[v.x], 1u);
        atomicAdd(&hist[v.y], 1u);
        atomicAdd(&hist[v.z], 1u);
        atomicAdd(&hist[v.w], 1u);
    } else {
        for (int j = i4; j < n; ++j) atomicAdd(&hist[idx[j]], 1u);
    }
}

// ---------------- launch ----------------

extern "C" void kernel_launch(void* const* d_in, const int* in_sizes, int n_in,
                              void* d_out, int out_size, void* d_ws, size_t ws_size,
                              hipStream_t stream) {
    const int* eb_input = (const int*)d_in[0];
    // d_in[1] (eb_offset) irrelevant: sum over all bags == sum over all indices.
    const float* W = (const float*)d_in[2];
    float* out = (float*)d_out;
    int n_idx = in_sizes[0];

    const size_t fill_bytes = 16384;                              // 245*16 u32 padded
    const size_t scat_bytes = (size_t)NBUCKETS * CAPACITY * 2;    // 9,031,680
    const size_t hist_off = fill_bytes + scat_bytes;              // 9,048,064 (16B aligned)
    const size_t need = hist_off + (size_t)VOCAB * 4;             // ~13.05 MB

    if (ws_size >= need) {
        unsigned int* fill = (unsigned int*)d_ws;
        unsigned short* scat = (unsigned short*)((char*)d_ws + fill_bytes);
        unsigned int* hist = (unsigned int*)((char*)d_ws + hist_off);

        zero_small_kernel<<<(NBUCKETS * FILL_STRIDE + 255) / 256, 256, 0, stream>>>(fill, out);
        int ablocks = (n_idx + 4095) / 4096;
        scatter_kernel<<<ablocks, 256, 0, stream>>>(eb_input, n_idx, fill, scat);
        bucket_hist_kernel<<<NBUCKETS, 256, 0, stream>>>(scat, fill, hist);
        reduce_kernel<<<NUM_TABLES * RBLOCKS_PER_TABLE, RTHREADS, 0, stream>>>(W, hist, out);
    } else {
        unsigned int* hist = (unsigned int*)d_ws;
        int zblocks = (VOCAB / 4 + 255) / 256;
        zero_kernel_fb<<<zblocks, 256, 0, stream>>>(hist, out);
        int hthreads = (n_idx + 3) / 4;
        int hblocks = (hthreads + 255) / 256;
        hist_kernel_fb<<<hblocks, 256, 0, stream>>>(eb_input, hist, n_idx);
        reduce_kernel<<<NUM_TABLES * RBLOCKS_PER_TABLE, RTHREADS, 0, stream>>>(W, hist, out);
    }
}

// Round 3
// 235.058 us; speedup vs baseline: 1.4435x; 1.0684x over previous
//
#include <hip/hip_runtime.h>

#define VOCAB 1000000
#define NUM_TABLES 10
#define OUT_SIZE 26
#define BUCKET_BITS 12
#define BPB 4096                // bins per bucket
#define NBUCKETS 245            // ceil(1e6/4096)
#define CHUNK 4096              // indices per scatter block
#define MAXSRC 1024             // max scatter blocks supported by fast path
#define RBLOCKS_PER_TABLE 128
#define RTHREADS 256

// ---------------- fast path ----------------

// Partition indices by bucket (idx>>12) into each block's PRIVATE dense region.
// No global atomics: per-block LDS ranks + LDS scan give deterministic layout.
__global__ void __launch_bounds__(256) scatter_kernel(
    const int* __restrict__ idx, int n,
    unsigned short* __restrict__ scat,   // [nsrc][CHUNK] u16 (bin within bucket)
    unsigned int* __restrict__ gs32)     // [NBUCKETS][MAXSRC]: start | count<<16
{
    __shared__ unsigned int lcount[256];
    __shared__ unsigned int sc[256];
    const int tid = threadIdx.x;
    lcount[tid] = 0u;
    __syncthreads();

    const int4* idx4 = (const int4*)idx;
    const int n4 = n >> 2;
    const int base4 = blockIdx.x * (CHUNK / 4);
    int4 q[4];
    bool val[4];
    unsigned rank[16];
    unsigned bkt[16];
#pragma unroll
    for (int j = 0; j < 4; ++j) {
        int i4 = base4 + j * 256 + tid;
        val[j] = (i4 < n4);
        if (val[j]) q[j] = idx4[i4];
    }
    // pass 1: per-element rank within (block, bucket)
#pragma unroll
    for (int j = 0; j < 4; ++j) {
        if (val[j]) {
            unsigned v[4] = {(unsigned)q[j].x, (unsigned)q[j].y, (unsigned)q[j].z, (unsigned)q[j].w};
#pragma unroll
            for (int e = 0; e < 4; ++e) {
                bkt[j * 4 + e] = v[e] >> BUCKET_BITS;
                rank[j * 4 + e] = atomicAdd(&lcount[bkt[j * 4 + e]], 1u);
            }
        }
    }
    // tail (n%4) handled by last block, thread 0 (dead code for n=4M)
    unsigned trank[3], tbkt[3];
    int tcnt = 0;
    if (blockIdx.x == gridDim.x - 1 && tid == 0) {
        for (int i = n4 * 4; i < n; ++i) {
            unsigned u = (unsigned)idx[i];
            tbkt[tcnt] = u >> BUCKET_BITS;
            trank[tcnt] = atomicAdd(&lcount[tbkt[tcnt]], 1u);
            ++tcnt;
        }
    }
    __syncthreads();
    // inclusive scan over 245 bucket counts (padded to 256)
    unsigned cnt = (tid < NBUCKETS) ? lcount[tid] : 0u;
    sc[tid] = cnt;
    __syncthreads();
#pragma unroll
    for (int off = 1; off < 256; off <<= 1) {
        unsigned v = sc[tid];
        unsigned a = (tid >= off) ? sc[tid - off] : 0u;
        __syncthreads();
        sc[tid] = v + a;
        __syncthreads();
    }
    unsigned excl = sc[tid] - cnt;
    if (tid < NBUCKETS) gs32[tid * MAXSRC + blockIdx.x] = excl | (cnt << 16);
    lcount[tid] = excl;   // reuse as per-bucket base for pass 2
    __syncthreads();
    // pass 2: dense grouped write into this block's private 8KB region
    unsigned short* myscat = scat + (size_t)blockIdx.x * CHUNK;
#pragma unroll
    for (int j = 0; j < 4; ++j) {
        if (val[j]) {
            unsigned v[4] = {(unsigned)q[j].x, (unsigned)q[j].y, (unsigned)q[j].z, (unsigned)q[j].w};
#pragma unroll
            for (int e = 0; e < 4; ++e) {
                unsigned k = j * 4 + e;
                myscat[lcount[bkt[k]] + rank[k]] = (unsigned short)(v[e] & (BPB - 1));
            }
        }
    }
    if (blockIdx.x == gridDim.x - 1 && tid == 0) {
        for (int i = 0; i < tcnt; ++i) {
            unsigned u = (unsigned)idx[n4 * 4 + i];
            myscat[lcount[tbkt[i]] + trank[i]] = (unsigned short)(u & (BPB - 1));
        }
    }
}

__device__ inline float wave_reduce(float v) {
#pragma unroll
    for (int o = 32; o > 0; o >>= 1) v += __shfl_down(v, o, 64);
    return v;
}

// One block per bucket: build 4096-bin LDS hist from all source regions,
// then stream W[t, bucket rows] for all 10 tables. Plain stores of partials.
__global__ void __launch_bounds__(1024) fused_kernel(
    const unsigned short* __restrict__ scat,
    const unsigned int* __restrict__ gs32, int nsrc,
    const float* __restrict__ W,
    float* __restrict__ partials)
{
    __shared__ unsigned int h[BPB];
    const int b = blockIdx.x;
    const int tid = threadIdx.x;
    for (int i = tid; i < BPB; i += 1024) h[i] = 0u;
    __syncthreads();
    if (tid < nsrc) {
        unsigned g32 = gs32[b * MAXSRC + tid];
        unsigned s = g32 & 0xffffu, c = g32 >> 16;
        const unsigned short* p = scat + (size_t)tid * CHUNK + s;
        for (unsigned k = 0; k < c; ++k) atomicAdd(&h[p[k]], 1u);
    }
    __syncthreads();

    float acc[NUM_TABLES][3];
#pragma unroll
    for (int t = 0; t < NUM_TABLES; ++t) { acc[t][0] = 0.f; acc[t][1] = 0.f; acc[t][2] = 0.f; }

    const int ngroups = min(BPB / 4, (VOCAB - b * BPB) / 4);  // 1024 (144 for b=244)
    const int g = tid;
    if (g < ngroups) {
        uint4 c4 = ((const uint4*)h)[g];
        float c0 = (float)c4.x, c1 = (float)c4.y, c2 = (float)c4.z, c3 = (float)c4.w;
        size_t w4base = (size_t)b * 3072 + 3 * (size_t)g;  // in float4 units
#pragma unroll
        for (int t = 0; t < NUM_TABLES; ++t) {
            const float4* W4 = ((const float4*)W) + (size_t)t * 750000 + w4base;
            float4 w0 = W4[0];
            float4 w1 = W4[1];
            float4 w2 = W4[2];
            acc[t][0] += c0 * w0.x + c1 * w0.w + c2 * w1.z + c3 * w2.y;
            acc[t][1] += c0 * w0.y + c1 * w1.x + c2 * w1.w + c3 * w2.z;
            acc[t][2] += c0 * w0.z + c1 * w1.y + c2 * w2.x + c3 * w2.w;
        }
    }
    __syncthreads();          // all h reads done; reuse LDS as float scratch
    float* sf = (float*)h;    // 30 * 16 floats
    const int wave = tid >> 6, lane = tid & 63;
#pragma unroll
    for (int t = 0; t < NUM_TABLES; ++t)
#pragma unroll
        for (int d = 0; d < 3; ++d) {
            float v = wave_reduce(acc[t][d]);
            if (lane == 0) sf[(t * 3 + d) * 16 + wave] = v;
        }
    __syncthreads();
    if (tid < 30) {
        float s = 0.f;
#pragma unroll
        for (int w = 0; w < 16; ++w) s += sf[tid * 16 + w];
        partials[b * 32 + tid] = s;
    }
}

__global__ void __launch_bounds__(256) final_kernel(const float* __restrict__ partials,
                                                    float* __restrict__ out) {
    __shared__ float red[256];
    __shared__ float tot[32];
    const int tid = threadIdx.x;
    const int v = tid & 31, c = tid >> 5;  // 8 chunks
    float s = 0.f;
    if (v < 30)
        for (int b = c; b < NBUCKETS; b += 8) s += partials[b * 32 + v];
    red[tid] = s;
    __syncthreads();
    if (tid < 32) {
        float t2 = 0.f;
#pragma unroll
        for (int cc = 0; cc < 8; ++cc) t2 += red[cc * 32 + tid];
        tot[tid] = t2;
    }
    __syncthreads();
    if (tid < OUT_SIZE) {
        float r;
        if (tid < 15) r = tot[tid];
        else if (tid == 15) r = tot[15] + tot[16] + tot[17];
        else if (tid == 16) r = tot[18] + tot[19] + tot[20];
        else r = tot[tid + 4];
        out[tid] = r;
    }
}

// ---------------- fallback path (R1, proven) ----------------

__global__ void zero_kernel_fb(unsigned int* __restrict__ hist, float* __restrict__ out) {
    int i = blockIdx.x * blockDim.x + threadIdx.x;
    int n4 = VOCAB / 4;
    if (i < n4) ((uint4*)hist)[i] = make_uint4(0u, 0u, 0u, 0u);
    if (i < OUT_SIZE) out[i] = 0.0f;
}

__global__ void hist_kernel_fb(const int* __restrict__ idx, unsigned int* __restrict__ hist, int n) {
    int i = blockIdx.x * blockDim.x + threadIdx.x;
    int i4 = i * 4;
    if (i4 + 3 < n) {
        int4 v = ((const int4*)idx)[i];
        atomicAdd(&hist[v.x], 1u);
        atomicAdd(&hist[v.y], 1u);
        atomicAdd(&hist[v.z], 1u);
        atomicAdd(&hist[v.w], 1u);
    } else {
        for (int j = i4; j < n; ++j) atomicAdd(&hist[idx[j]], 1u);
    }
}

__global__ void __launch_bounds__(RTHREADS) reduce_kernel_fb(const float* __restrict__ W,
                                                             const unsigned int* __restrict__ hist,
                                                             float* __restrict__ out) {
    const int t = blockIdx.x / RBLOCKS_PER_TABLE;
    const int b = blockIdx.x % RBLOCKS_PER_TABLE;
    const float4* __restrict__ W4 = (const float4*)(W + (size_t)t * VOCAB * 3);
    const uint4* __restrict__ h4 = (const uint4*)hist;
    const int ngroups = VOCAB / 4;
    float a0 = 0.f, a1 = 0.f, a2 = 0.f;
    const int stride = RBLOCKS_PER_TABLE * RTHREADS;
    for (int g = b * RTHREADS + (int)threadIdx.x; g < ngroups; g += stride) {
        uint4 c4 = h4[g];
        float4 w0 = W4[3 * g + 0];
        float4 w1 = W4[3 * g + 1];
        float4 w2 = W4[3 * g + 2];
        float c0 = (float)c4.x, c1 = (float)c4.y, c2 = (float)c4.z, c3 = (float)c4.w;
        a0 += c0 * w0.x + c1 * w0.w + c2 * w1.z + c3 * w2.y;
        a1 += c0 * w0.y + c1 * w1.x + c2 * w1.w + c3 * w2.z;
        a2 += c0 * w0.z + c1 * w1.y + c2 * w2.x + c3 * w2.w;
    }
    a0 = wave_reduce(a0);
    a1 = wave_reduce(a1);
    a2 = wave_reduce(a2);
    __shared__ float s[3][4];
    int wave = threadIdx.x >> 6;
    int lane = threadIdx.x & 63;
    if (lane == 0) { s[0][wave] = a0; s[1][wave] = a1; s[2][wave] = a2; }
    __syncthreads();
    if (threadIdx.x == 0) {
        float r0 = s[0][0] + s[0][1] + s[0][2] + s[0][3];
        float r1 = s[1][0] + s[1][1] + s[1][2] + s[1][3];
        float r2 = s[2][0] + s[2][1] + s[2][2] + s[2][3];
        if (t == 5) atomicAdd(&out[15], r0 + r1 + r2);
        else if (t == 6) atomicAdd(&out[16], r0 + r1 + r2);
        else {
            int base = (t < 5) ? t * 3 : 17 + (t - 7) * 3;
            atomicAdd(&out[base + 0], r0);
            atomicAdd(&out[base + 1], r1);
            atomicAdd(&out[base + 2], r2);
        }
    }
}

// ---------------- launch ----------------

extern "C" void kernel_launch(void* const* d_in, const int* in_sizes, int n_in,
                              void* d_out, int out_size, void* d_ws, size_t ws_size,
                              hipStream_t stream) {
    const int* eb_input = (const int*)d_in[0];
    // d_in[1] (eb_offset) irrelevant: sum over all bags == sum over all indices.
    const float* W = (const float*)d_in[2];
    float* out = (float*)d_out;
    int n_idx = in_sizes[0];

    const int nsrc = (n_idx + CHUNK - 1) / CHUNK;
    const size_t scat_bytes = (size_t)MAXSRC * CHUNK * 2;        // 8,388,608
    const size_t gs_off = scat_bytes;
    const size_t gs_bytes = (size_t)NBUCKETS * MAXSRC * 4;       // 1,003,520
    const size_t part_off = gs_off + gs_bytes;
    const size_t need = part_off + (size_t)NBUCKETS * 32 * 4;    // ~9.42 MB

    if (nsrc <= MAXSRC && ws_size >= need) {
        unsigned short* scat = (unsigned short*)d_ws;
        unsigned int* gs32 = (unsigned int*)((char*)d_ws + gs_off);
        float* partials = (float*)((char*)d_ws + part_off);

        scatter_kernel<<<nsrc, 256, 0, stream>>>(eb_input, n_idx, scat, gs32);
        fused_kernel<<<NBUCKETS, 1024, 0, stream>>>(scat, gs32, nsrc, W, partials);
        final_kernel<<<1, 256, 0, stream>>>(partials, out);
    } else {
        unsigned int* hist = (unsigned int*)d_ws;
        int zblocks = (VOCAB / 4 + 255) / 256;
        zero_kernel_fb<<<zblocks, 256, 0, stream>>>(hist, out);
        int hthreads = (n_idx + 3) / 4;
        int hblocks = (hthreads + 255) / 256;
        hist_kernel_fb<<<hblocks, 256, 0, stream>>>(eb_input, hist, n_idx);
        reduce_kernel_fb<<<NUM_TABLES * RBLOCKS_PER_TABLE, RTHREADS, 0, stream>>>(W, hist, out);
    }
}

// Round 4
// 209.183 us; speedup vs baseline: 1.6221x; 1.1237x over previous
//
#include <hip/hip_runtime.h>

#define VOCAB 1000000
#define NUM_TABLES 10
#define OUT_SIZE 26
#define BUCKET_BITS 12
#define BPB 4096                // bins per bucket
#define NBUCKETS 245            // ceil(1e6/4096)
#define CHUNK 4096              // indices per scatter block
#define MAXSRC 1024             // max scatter blocks supported by fast path
#define RBLOCKS_PER_TABLE 256
#define NRBLK (NUM_TABLES * RBLOCKS_PER_TABLE)   // 2560
#define RTHREADS 256

// ---------------- fast path ----------------

// Partition indices by bucket (idx>>12) into each block's PRIVATE dense region.
// No global atomics; pass-2 permutation staged in LDS, dumped coalesced.
__global__ void __launch_bounds__(256) scatter_kernel(
    const int* __restrict__ idx, int n,
    unsigned short* __restrict__ scat,   // [nsrc][CHUNK] u16 (bin within bucket)
    unsigned int* __restrict__ gs32)     // [NBUCKETS][MAXSRC]: start | count<<16
{
    __shared__ unsigned int lcount[256];
    __shared__ unsigned int sc[256];
    __shared__ unsigned short stage[CHUNK];   // 8 KB
    const int tid = threadIdx.x;
    lcount[tid] = 0u;
    __syncthreads();

    const int4* idx4 = (const int4*)idx;
    const int n4 = n >> 2;
    const int base4 = blockIdx.x * (CHUNK / 4);
    int4 q[4];
    bool val[4];
    unsigned rank[16];
    unsigned bkt[16];
#pragma unroll
    for (int j = 0; j < 4; ++j) {
        int i4 = base4 + j * 256 + tid;
        val[j] = (i4 < n4);
        if (val[j]) q[j] = idx4[i4];
    }
    // pass 1: per-element rank within (block, bucket)
#pragma unroll
    for (int j = 0; j < 4; ++j) {
        if (val[j]) {
            unsigned v[4] = {(unsigned)q[j].x, (unsigned)q[j].y, (unsigned)q[j].z, (unsigned)q[j].w};
#pragma unroll
            for (int e = 0; e < 4; ++e) {
                bkt[j * 4 + e] = v[e] >> BUCKET_BITS;
                rank[j * 4 + e] = atomicAdd(&lcount[bkt[j * 4 + e]], 1u);
            }
        }
    }
    // tail (n%4): last block, thread 0 (dead code for n=4M)
    unsigned trank[3], tbkt[3];
    int tcnt = 0;
    if (blockIdx.x == gridDim.x - 1 && tid == 0) {
        for (int i = n4 * 4; i < n; ++i) {
            unsigned u = (unsigned)idx[i];
            tbkt[tcnt] = u >> BUCKET_BITS;
            trank[tcnt] = atomicAdd(&lcount[tbkt[tcnt]], 1u);
            ++tcnt;
        }
    }
    __syncthreads();
    // inclusive scan over 245 bucket counts (padded to 256)
    unsigned cnt = (tid < NBUCKETS) ? lcount[tid] : 0u;
    sc[tid] = cnt;
    __syncthreads();
#pragma unroll
    for (int off = 1; off < 256; off <<= 1) {
        unsigned v = sc[tid];
        unsigned a = (tid >= off) ? sc[tid - off] : 0u;
        __syncthreads();
        sc[tid] = v + a;
        __syncthreads();
    }
    unsigned excl = sc[tid] - cnt;
    if (tid < NBUCKETS) gs32[tid * MAXSRC + blockIdx.x] = excl | (cnt << 16);
    lcount[tid] = excl;   // reuse as per-bucket base
    __syncthreads();
    // pass 2: scatter into LDS stage (unique positions, no atomics)
#pragma unroll
    for (int j = 0; j < 4; ++j) {
        if (val[j]) {
            unsigned v[4] = {(unsigned)q[j].x, (unsigned)q[j].y, (unsigned)q[j].z, (unsigned)q[j].w};
#pragma unroll
            for (int e = 0; e < 4; ++e) {
                unsigned k = j * 4 + e;
                stage[lcount[bkt[k]] + rank[k]] = (unsigned short)(v[e] & (BPB - 1));
            }
        }
    }
    if (blockIdx.x == gridDim.x - 1 && tid == 0) {
        for (int i = 0; i < tcnt; ++i) {
            unsigned u = (unsigned)idx[n4 * 4 + i];
            stage[lcount[tbkt[i]] + trank[i]] = (unsigned short)(u & (BPB - 1));
        }
    }
    __syncthreads();
    // coalesced dump: 4096 u16 = 512 uint4
    uint4* dst = (uint4*)(scat + (size_t)blockIdx.x * CHUNK);
    const uint4* src = (const uint4*)stage;
#pragma unroll
    for (int j = 0; j < 2; ++j) dst[j * 256 + tid] = src[j * 256 + tid];
}

// One block per bucket: build 4096-bin hist in LDS, write coalesced.
__global__ void __launch_bounds__(1024) bucket_hist_kernel(
    const unsigned short* __restrict__ scat,
    const unsigned int* __restrict__ gs32, int nsrc,
    unsigned int* __restrict__ hist)
{
    __shared__ unsigned int h[BPB];
    const int b = blockIdx.x;
    const int tid = threadIdx.x;
    for (int i = tid; i < BPB; i += 1024) h[i] = 0u;
    __syncthreads();
    if (tid < nsrc) {
        unsigned g32 = gs32[b * MAXSRC + tid];
        unsigned s = g32 & 0xffffu, c = g32 >> 16;
        const unsigned short* p = scat + (size_t)tid * CHUNK + s;
        unsigned k = 0;
        for (; k + 4 <= c; k += 4) {
            unsigned short a0 = p[k], a1 = p[k + 1], a2 = p[k + 2], a3 = p[k + 3];
            atomicAdd(&h[a0], 1u);
            atomicAdd(&h[a1], 1u);
            atomicAdd(&h[a2], 1u);
            atomicAdd(&h[a3], 1u);
        }
        for (; k < c; ++k) atomicAdd(&h[p[k]], 1u);
    }
    __syncthreads();
    int nb4 = min(BPB, VOCAB - b * BPB) >> 2;   // 1024 (144 for b=244)
    uint4* dst = (uint4*)(hist + (size_t)b * BPB);
    const uint4* src = (const uint4*)h;
    if (tid < nb4) dst[tid] = src[tid];
}

__device__ inline float wave_reduce(float v) {
#pragma unroll
    for (int o = 32; o > 0; o >>= 1) v += __shfl_down(v, o, 64);
    return v;
}

// Wide streaming reduce: hist + W -> per-block partials (no atomics).
__global__ void __launch_bounds__(RTHREADS) reduce_kernel(const float* __restrict__ W,
                                                          const unsigned int* __restrict__ hist,
                                                          float* __restrict__ partials) {
    const int t = blockIdx.x / RBLOCKS_PER_TABLE;
    const int b = blockIdx.x % RBLOCKS_PER_TABLE;
    const float4* __restrict__ W4 = (const float4*)(W + (size_t)t * VOCAB * 3);
    const uint4* __restrict__ h4 = (const uint4*)hist;
    const int ngroups = VOCAB / 4;  // 250000
    float a0 = 0.f, a1 = 0.f, a2 = 0.f;
    const int stride = RBLOCKS_PER_TABLE * RTHREADS;
    for (int g = b * RTHREADS + (int)threadIdx.x; g < ngroups; g += stride) {
        uint4 c4 = h4[g];
        float4 w0 = W4[3 * g + 0];
        float4 w1 = W4[3 * g + 1];
        float4 w2 = W4[3 * g + 2];
        float c0 = (float)c4.x, c1 = (float)c4.y, c2 = (float)c4.z, c3 = (float)c4.w;
        a0 += c0 * w0.x + c1 * w0.w + c2 * w1.z + c3 * w2.y;
        a1 += c0 * w0.y + c1 * w1.x + c2 * w1.w + c3 * w2.z;
        a2 += c0 * w0.z + c1 * w1.y + c2 * w2.x + c3 * w2.w;
    }
    a0 = wave_reduce(a0);
    a1 = wave_reduce(a1);
    a2 = wave_reduce(a2);
    __shared__ float s[3][4];
    int wave = threadIdx.x >> 6;
    int lane = threadIdx.x & 63;
    if (lane == 0) { s[0][wave] = a0; s[1][wave] = a1; s[2][wave] = a2; }
    __syncthreads();
    if (threadIdx.x == 0) {
        partials[0 * NRBLK + blockIdx.x] = s[0][0] + s[0][1] + s[0][2] + s[0][3];
        partials[1 * NRBLK + blockIdx.x] = s[1][0] + s[1][1] + s[1][2] + s[1][3];
        partials[2 * NRBLK + blockIdx.x] = s[2][0] + s[2][1] + s[2][2] + s[2][3];
    }
}

__global__ void __launch_bounds__(1024) final_kernel(const float* __restrict__ partials,
                                                     float* __restrict__ out) {
    __shared__ float ts[32];
    const int tid = threadIdx.x;
    const int srs = tid >> 5;      // series 0..31 (use <30): s = t*3+d
    const int j = tid & 31;
    float v = 0.f;
    if (srs < 30) {
        const int t = srs / 3, d = srs % 3;
        const float* p = partials + (size_t)d * NRBLK + t * RBLOCKS_PER_TABLE;
#pragma unroll
        for (int k = 0; k < RBLOCKS_PER_TABLE / 32; ++k) v += p[k * 32 + j];
    }
#pragma unroll
    for (int off = 16; off > 0; off >>= 1) v += __shfl_down(v, off);
    if (j == 0 && srs < 30) ts[srs] = v;
    __syncthreads();
    if (tid < OUT_SIZE) {
        float r;
        if (tid < 15) r = ts[tid];
        else if (tid == 15) r = ts[15] + ts[16] + ts[17];
        else if (tid == 16) r = ts[18] + ts[19] + ts[20];
        else r = ts[tid + 4];
        out[tid] = r;
    }
}

// ---------------- fallback path (R1, proven) ----------------

__global__ void zero_kernel_fb(unsigned int* __restrict__ hist, float* __restrict__ out) {
    int i = blockIdx.x * blockDim.x + threadIdx.x;
    int n4 = VOCAB / 4;
    if (i < n4) ((uint4*)hist)[i] = make_uint4(0u, 0u, 0u, 0u);
    if (i < OUT_SIZE) out[i] = 0.0f;
}

__global__ void hist_kernel_fb(const int* __restrict__ idx, unsigned int* __restrict__ hist, int n) {
    int i = blockIdx.x * blockDim.x + threadIdx.x;
    int i4 = i * 4;
    if (i4 + 3 < n) {
        int4 v = ((const int4*)idx)[i];
        atomicAdd(&hist[v.x], 1u);
        atomicAdd(&hist[v.y], 1u);
        atomicAdd(&hist[v.z], 1u);
        atomicAdd(&hist[v.w], 1u);
    } else {
        for (int j = i4; j < n; ++j) atomicAdd(&hist[idx[j]], 1u);
    }
}

__global__ void __launch_bounds__(RTHREADS) reduce_kernel_fb(const float* __restrict__ W,
                                                             const unsigned int* __restrict__ hist,
                                                             float* __restrict__ out) {
    const int t = blockIdx.x / 64;
    const int b = blockIdx.x % 64;
    const float4* __restrict__ W4 = (const float4*)(W + (size_t)t * VOCAB * 3);
    const uint4* __restrict__ h4 = (const uint4*)hist;
    const int ngroups = VOCAB / 4;
    float a0 = 0.f, a1 = 0.f, a2 = 0.f;
    const int stride = 64 * RTHREADS;
    for (int g = b * RTHREADS + (int)threadIdx.x; g < ngroups; g += stride) {
        uint4 c4 = h4[g];
        float4 w0 = W4[3 * g + 0];
        float4 w1 = W4[3 * g + 1];
        float4 w2 = W4[3 * g + 2];
        float c0 = (float)c4.x, c1 = (float)c4.y, c2 = (float)c4.z, c3 = (float)c4.w;
        a0 += c0 * w0.x + c1 * w0.w + c2 * w1.z + c3 * w2.y;
        a1 += c0 * w0.y + c1 * w1.x + c2 * w1.w + c3 * w2.z;
        a2 += c0 * w0.z + c1 * w1.y + c2 * w2.x + c3 * w2.w;
    }
    a0 = wave_reduce(a0);
    a1 = wave_reduce(a1);
    a2 = wave_reduce(a2);
    __shared__ float s[3][4];
    int wave = threadIdx.x >> 6;
    int lane = threadIdx.x & 63;
    if (lane == 0) { s[0][wave] = a0; s[1][wave] = a1; s[2][wave] = a2; }
    __syncthreads();
    if (threadIdx.x == 0) {
        float r0 = s[0][0] + s[0][1] + s[0][2] + s[0][3];
        float r1 = s[1][0] + s[1][1] + s[1][2] + s[1][3];
        float r2 = s[2][0] + s[2][1] + s[2][2] + s[2][3];
        if (t == 5) atomicAdd(&out[15], r0 + r1 + r2);
        else if (t == 6) atomicAdd(&out[16], r0 + r1 + r2);
        else {
            int base = (t < 5) ? t * 3 : 17 + (t - 7) * 3;
            atomicAdd(&out[base + 0], r0);
            atomicAdd(&out[base + 1], r1);
            atomicAdd(&out[base + 2], r2);
        }
    }
}

// ---------------- launch ----------------

extern "C" void kernel_launch(void* const* d_in, const int* in_sizes, int n_in,
                              void* d_out, int out_size, void* d_ws, size_t ws_size,
                              hipStream_t stream) {
    const int* eb_input = (const int*)d_in[0];
    // d_in[1] (eb_offset) irrelevant: sum over all bags == sum over all indices.
    const float* W = (const float*)d_in[2];
    float* out = (float*)d_out;
    int n_idx = in_sizes[0];

    const int nsrc = (n_idx + CHUNK - 1) / CHUNK;
    const size_t scat_bytes = (size_t)MAXSRC * CHUNK * 2;        // 8,388,608
    const size_t gs_off = scat_bytes;
    const size_t gs_bytes = (size_t)NBUCKETS * MAXSRC * 4;       // 1,003,520
    const size_t hist_off = gs_off + gs_bytes;
    const size_t hist_bytes = (size_t)VOCAB * 4;                 // 4,000,000
    const size_t part_off = (hist_off + hist_bytes + 255) & ~(size_t)255;
    const size_t need = part_off + (size_t)3 * NRBLK * 4;        // ~13.4 MB

    if (nsrc <= MAXSRC && ws_size >= need) {
        unsigned short* scat = (unsigned short*)d_ws;
        unsigned int* gs32 = (unsigned int*)((char*)d_ws + gs_off);
        unsigned int* hist = (unsigned int*)((char*)d_ws + hist_off);
        float* partials = (float*)((char*)d_ws + part_off);

        scatter_kernel<<<nsrc, 256, 0, stream>>>(eb_input, n_idx, scat, gs32);
        bucket_hist_kernel<<<NBUCKETS, 1024, 0, stream>>>(scat, gs32, nsrc, hist);
        reduce_kernel<<<NRBLK, RTHREADS, 0, stream>>>(W, hist, partials);
        final_kernel<<<1, 1024, 0, stream>>>(partials, out);
    } else {
        unsigned int* hist = (unsigned int*)d_ws;
        int zblocks = (VOCAB / 4 + 255) / 256;
        zero_kernel_fb<<<zblocks, 256, 0, stream>>>(hist, out);
        int hthreads = (n_idx + 3) / 4;
        int hblocks = (hthreads + 255) / 256;
        hist_kernel_fb<<<hblocks, 256, 0, stream>>>(eb_input, hist, n_idx);
        reduce_kernel_fb<<<NUM_TABLES * 64, RTHREADS, 0, stream>>>(W, hist, out);
    }
}